// Round 9
// baseline (16496.191 us; speedup 1.0000x reference)
//
#include <hip/hip_runtime.h>

#define T_STEPS 4096
#define N_RES   2048
#define N_IN    64
#define N_OUT   64
#define LEAK    0.3f
#define NOISE_S 0.01f

#define NWG      256     // reservoir WGs (1 per CU)
#define RPW      8       // rows per WG
#define RPWAVE   2       // rows per compute wave (= one 8B store group)
#define NTHREADS 448     // waves 0-3 compute, 4-5 dual poll, 6 writer

typedef unsigned int uint32x4 __attribute__((ext_vector_type(4)));
typedef unsigned int uint32x2 __attribute__((ext_vector_type(2)));

// ---------------------------------------------------------------------------
// Kernel 1: it[t][n] = dot(u[t,:], W_in[n,:]) + 0.01*noise[t][n]
// ---------------------------------------------------------------------------
__global__ __launch_bounds__(256) void input_terms_kernel(
    const float* __restrict__ u, const float* __restrict__ noise,
    const float* __restrict__ W_in, float* __restrict__ it) {
  const int t = blockIdx.x;
  const int tid = threadIdx.x;
  __shared__ float su[N_IN];
  if (tid < N_IN) su[tid] = u[(size_t)t * N_IN + tid];
  __syncthreads();
  #pragma unroll
  for (int k = 0; k < N_RES / 256; ++k) {
    const int n = tid + 256 * k;
    const float4* wr = reinterpret_cast<const float4*>(W_in + (size_t)n * N_IN);
    float acc = 0.f;
    #pragma unroll
    for (int j = 0; j < N_IN / 4; ++j) {
      float4 w4 = wr[j];
      acc = fmaf(w4.x, su[4 * j + 0], acc);
      acc = fmaf(w4.y, su[4 * j + 1], acc);
      acc = fmaf(w4.z, su[4 * j + 2], acc);
      acc = fmaf(w4.w, su[4 * j + 3], acc);
    }
    it[(size_t)t * N_RES + n] = acc + NOISE_S * noise[(size_t)t * N_RES + n];
  }
}

// ---------------------------------------------------------------------------
// Kernel 2: persistent recurrence, 4B tagged state, specialized waves.
// 256 WGs x 448 threads (7 waves, 1 WG/CU).
//   waves 0-3: compute 2 rows each from LDS-resident W (64 KB; R7 proved
//              VGPR-parking gets spilled — VGPR_Count 80 < the 128 needed).
//              Only global op: lane 0's ONE tagged dwordx2 store per step.
//   waves 4,5: DUAL poll-only waves — two independent samplers halve the
//              expected detect delay of the last-arriving group; LDS fills
//              are idempotent (bit-identical tag-masked words). They never
//              store to global, so their vmcnt(0) covers only poll loads.
//   wave 6:    writer — records states[t-1] to it[] from LDS and stages
//              it[t+1] into LDS, keeping ALL HBM traffic off compute waves.
//
// State word = fp32 bits, low 2 mantissa bits = (step & 3); producer skew
// <= 2 steps => mod-4 tags disambiguate; <= 3 ulp perturbation (absmax has
// sat at 3.9e-3 >> this for all rounds). 8B group = 2 adjacent rows = one
// compute wave's output. s_0 = zeros in LDS, never polled.
// One __syncthreads per step for all 7 waves.
// ---------------------------------------------------------------------------
__global__ __launch_bounds__(NTHREADS, 1) void reservoir_kernel(
    const float* __restrict__ W, float* __restrict__ it,
    unsigned int* sbuf) {
  const int wg = blockIdx.x;
  const int tid = threadIdx.x;
  const int wave = tid >> 6;       // 0..6
  const int lane = tid & 63;
  const int R = wg * RPW;

  __shared__ float Wl[RPW * N_RES];   // 64 KB
  __shared__ float ls[2][N_RES];      // 16 KB state double buffer
  __shared__ float stg_it[2][RPW];    // input-term staging (writer -> compute)

  // Stage this WG's 8 W rows into LDS once.
  {
    const float4* Wg = reinterpret_cast<const float4*>(W + (size_t)R * N_RES);
    float4* Wd = reinterpret_cast<float4*>(Wl);
    for (int idx = tid; idx < RPW * N_RES / 4; idx += NTHREADS)
      Wd[idx] = Wg[idx];
  }
  // s_0 = zeros (reset_state=True).
  for (int idx = tid; idx < N_RES; idx += NTHREADS) ls[0][idx] = 0.f;
  if (wave == 6 && lane < RPW) stg_it[0][lane] = it[R + lane];
  __syncthreads();

  if (wave < 4) {
    // ================= compute waves (2 rows each) =================
    const int r0 = R + wave * RPWAVE;
    const float4* W0 = reinterpret_cast<const float4*>(Wl + (size_t)(RPWAVE * wave + 0) * N_RES);
    const float4* W1 = reinterpret_cast<const float4*>(Wl + (size_t)(RPWAVE * wave + 1) * N_RES);

    for (unsigned int t = 0; t < T_STEPS; ++t) {
      const float* cur = ls[t & 1];
      float* nxt = ls[(t + 1) & 1];
      unsigned int* swb = sbuf + ((t + 1) & 1) * N_RES;

      const float4* S4 = reinterpret_cast<const float4*>(cur);
      float a0 = 0.f, a1 = 0.f;
      #pragma unroll
      for (int j = 0; j < 8; ++j) {
        const float4 s4 = S4[lane + 64 * j];
        const float4 x0 = W0[lane + 64 * j];
        const float4 x1 = W1[lane + 64 * j];
        a0 = fmaf(x0.x, s4.x, a0); a0 = fmaf(x0.y, s4.y, a0);
        a0 = fmaf(x0.z, s4.z, a0); a0 = fmaf(x0.w, s4.w, a0);
        a1 = fmaf(x1.x, s4.x, a1); a1 = fmaf(x1.y, s4.y, a1);
        a1 = fmaf(x1.z, s4.z, a1); a1 = fmaf(x1.w, s4.w, a1);
      }
      #pragma unroll
      for (int off = 32; off > 0; off >>= 1) {
        a0 += __shfl_xor(a0, off);
        a1 += __shfl_xor(a1, off);
      }

      const unsigned int tg = (t + 1) & 3u;
      unsigned int pkw = 0;
      if (lane < RPWAVE) {
        const float a = lane ? a1 : a0;
        const float itv = stg_it[t & 1][wave * RPWAVE + lane];  // staged by wave 6
        const float h = tanhf(itv + a);
        const float sold = cur[r0 + lane];
        const float snew = (1.0f - LEAK) * sold + LEAK * h;
        pkw = (__float_as_uint(snew) & ~3u) | tg;
        // Own value straight into next LDS buffer (bit-identical to what
        // remote WGs read); poll waves skip own chunks, wave 6 records it.
        nxt[r0 + lane] = __uint_as_float(pkw);
      }
      // Pack this wave's 2 rows -> one tagged dwordx2, lane 0 fires it.
      uint32x2 pk;
      pk[0] = __shfl(pkw, 0);
      pk[1] = __shfl(pkw, 1);
      if (lane == 0) {
        uint32x2* dst = reinterpret_cast<uint32x2*>(swb + r0);
        asm volatile("global_store_dwordx2 %0, %1, off sc0 sc1"
                     :: "v"(dst), "v"(pk) : "memory");
      }
      __syncthreads();  // nxt complete (own writes + poll-wave remote fills)
    }
  } else if (wave < 6) {
    // ============ dual poll waves (4,5) — NEVER store to global ============
    // Lane l covers 16B chunks c = l + 64k (k=0..7); each chunk = two 8B
    // groups, checked/filled independently. Own WG's rows (2 chunks) are
    // filled by compute waves directly -> masked out.
    unsigned int own = 0;
    #pragma unroll
    for (int cc = 0; cc < 2; ++cc) {
      const int c = 2 * wg + cc;
      if ((c & 63) == lane) own |= 3u << (2 * (c >> 6));
    }
    for (unsigned int t = 0; t < T_STEPS; ++t) {
      if (t + 1 < T_STEPS) {
        unsigned int* swb = sbuf + ((t + 1) & 1) * N_RES;
        uint32x2* dst2 = reinterpret_cast<uint32x2*>(ls[(t + 1) & 1]);
        const unsigned int tg = (t + 1) & 3u;
        const char* p0 = (const char*)swb + lane * 16;
        const char* p1 = p0 + 4096;
        unsigned int need = 0xFFFFu & ~own;
        for (;;) {
          uint32x4 v0, v1, v2, v3, v4, v5, v6, v7;
          asm volatile(
              "global_load_dwordx4 %0, %8, off sc0 sc1\n\t"
              "global_load_dwordx4 %1, %8, off offset:1024 sc0 sc1\n\t"
              "global_load_dwordx4 %2, %8, off offset:2048 sc0 sc1\n\t"
              "global_load_dwordx4 %3, %8, off offset:3072 sc0 sc1\n\t"
              "global_load_dwordx4 %4, %9, off sc0 sc1\n\t"
              "global_load_dwordx4 %5, %9, off offset:1024 sc0 sc1\n\t"
              "global_load_dwordx4 %6, %9, off offset:2048 sc0 sc1\n\t"
              "global_load_dwordx4 %7, %9, off offset:3072 sc0 sc1\n\t"
              "s_waitcnt vmcnt(0)"
              : "=&v"(v0), "=&v"(v1), "=&v"(v2), "=&v"(v3),
                "=&v"(v4), "=&v"(v5), "=&v"(v6), "=&v"(v7)
              : "v"(p0), "v"(p1)
              : "memory");
          #define CHK_CHUNK(vk, k)                                            \
            do {                                                              \
              const unsigned int blo = 1u << (2 * (k));                       \
              const unsigned int bhi = 2u << (2 * (k));                       \
              if ((need & blo) && ((((vk[0] ^ tg) | (vk[1] ^ tg)) & 3u) == 0u)) { \
                uint32x2 h_; h_[0] = vk[0]; h_[1] = vk[1];                    \
                dst2[2 * (lane + 64 * (k))] = h_; need &= ~blo;               \
              }                                                               \
              if ((need & bhi) && ((((vk[2] ^ tg) | (vk[3] ^ tg)) & 3u) == 0u)) { \
                uint32x2 h_; h_[0] = vk[2]; h_[1] = vk[3];                    \
                dst2[2 * (lane + 64 * (k)) + 1] = h_; need &= ~bhi;           \
              }                                                               \
            } while (0)
          CHK_CHUNK(v0, 0); CHK_CHUNK(v1, 1); CHK_CHUNK(v2, 2); CHK_CHUNK(v3, 3);
          CHK_CHUNK(v4, 4); CHK_CHUNK(v5, 5); CHK_CHUNK(v6, 6); CHK_CHUNK(v7, 7);
          #undef CHK_CHUNK
          if (__all(need == 0u)) break;
          __builtin_amdgcn_s_sleep(1);
        }
      }
      __syncthreads();
    }
  } else {
    // ================= writer wave (wave 6) =================
    for (unsigned int t = 0; t < T_STEPS; ++t) {
      if (lane < RPW) {
        if (t >= 1)
          it[(size_t)(t - 1) * N_RES + R + lane] = ls[t & 1][R + lane];
        if (t + 1 < T_STEPS)
          stg_it[(t + 1) & 1][lane] = it[(size_t)(t + 1) * N_RES + R + lane];
      }
      __syncthreads();
    }
    if (lane < RPW)  // final state record (filled into ls[0] at t = T-1)
      it[(size_t)(T_STEPS - 1) * N_RES + R + lane] = ls[T_STEPS & 1][R + lane];
  }
}

// ---------------------------------------------------------------------------
// Kernel 3: out[t][o] = dot(states[t,:], rw[o,:]) + rb[o]
// ---------------------------------------------------------------------------
__global__ __launch_bounds__(256) void readout_kernel(
    const float* __restrict__ states, const float* __restrict__ rw,
    const float* __restrict__ rb, float* __restrict__ out) {
  const int t = blockIdx.x;
  const int tid = threadIdx.x;
  const int o = tid & 63;
  const int q = tid >> 6;  // 0..3
  __shared__ float ss[N_RES];
  #pragma unroll
  for (int k = 0; k < N_RES / 256; ++k)
    ss[tid + 256 * k] = states[(size_t)t * N_RES + tid + 256 * k];
  __syncthreads();

  const float4* r4 = reinterpret_cast<const float4*>(rw + (size_t)o * N_RES + q * 512);
  float acc = 0.f;
  #pragma unroll 8
  for (int j = 0; j < 128; ++j) {
    float4 w4 = r4[j];
    const int base = q * 512 + 4 * j;
    acc = fmaf(w4.x, ss[base + 0], acc);
    acc = fmaf(w4.y, ss[base + 1], acc);
    acc = fmaf(w4.z, ss[base + 2], acc);
    acc = fmaf(w4.w, ss[base + 3], acc);
  }
  __shared__ float red[256];
  red[tid] = acc;
  __syncthreads();
  if (tid < 64) {
    float v = red[tid] + red[tid + 64] + red[tid + 128] + red[tid + 192];
    out[(size_t)t * N_OUT + tid] = v + rb[tid];
  }
}

// ---------------------------------------------------------------------------
extern "C" void kernel_launch(void* const* d_in, const int* in_sizes, int n_in,
                              void* d_out, int out_size, void* d_ws, size_t ws_size,
                              hipStream_t stream) {
  const float* u     = (const float*)d_in[0];  // [4096, 64]
  const float* noise = (const float*)d_in[1];  // [4096, 2048]
  const float* W_in  = (const float*)d_in[2];  // [2048, 64]
  const float* W     = (const float*)d_in[3];  // [2048, 2048]
  const float* rw    = (const float*)d_in[4];  // [64, 2048]
  const float* rb    = (const float*)d_in[5];  // [64]
  float* out = (float*)d_out;                  // [4096, 64]

  float* it = (float*)d_ws;  // 32 MB: input terms, overwritten with states
  unsigned int* sbuf =
      (unsigned int*)((char*)d_ws + (size_t)T_STEPS * N_RES * sizeof(float));

  // Zero both tagged state buffers every call (0xAA poison would alias tag
  // bits; zeros are safe: stale tag = fresh-2 mod 4, never equal).
  hipMemsetAsync(sbuf, 0, 2 * N_RES * sizeof(unsigned int), stream);

  input_terms_kernel<<<T_STEPS, 256, 0, stream>>>(u, noise, W_in, it);

  void* args[] = {(void*)&W, (void*)&it, (void*)&sbuf};
  hipLaunchCooperativeKernel((void*)reservoir_kernel, dim3(NWG), dim3(NTHREADS),
                             args, 0, stream);

  readout_kernel<<<T_STEPS, 256, 0, stream>>>(it, rw, rb, out);
}